// Round 1
// baseline (238.576 us; speedup 1.0000x reference)
//
#include <hip/hip_runtime.h>

// Problem constants (match the reference file).
constexpr int DIM = 512;   // irreps dim for x, y, out
constexpr int C   = 16;    // channel multiplicity

// start[d] = first p such that index_out[p] >= d  (index_out is sorted).
// start[DIM] = nnz. One thread per d in [0, DIM].
__global__ void seg_starts_kernel(const int* __restrict__ io,
                                  int* __restrict__ start,
                                  int nnz, int dim) {
    int d = blockIdx.x * blockDim.x + threadIdx.x;
    if (d > dim) return;
    int lo = 0, hi = nnz;
    while (lo < hi) {
        int mid = (lo + hi) >> 1;
        if (io[mid] < d) lo = mid + 1; else hi = mid;
    }
    start[d] = lo;
}

// One block per n. Each thread owns (d, c-quad) output elements and loops
// over the sorted segment of paths whose index_out == d. No atomics.
__global__ __launch_bounds__(256) void tp_kernel(
    const float* __restrict__ x, const float* __restrict__ y,
    const float* __restrict__ scale,
    const int* __restrict__ i1, const int* __restrict__ i2,
    const int* __restrict__ start,
    float* __restrict__ out) {
    const int n = blockIdx.x;
    const float* __restrict__ xr = x + (size_t)n * (DIM * C);
    const float* __restrict__ yr = y + (size_t)n * (DIM * C);
    float* __restrict__ orow = out + (size_t)n * (DIM * C);

    const int c4   = (threadIdx.x & 3) << 2;  // channel quad offset: 0,4,8,12
    const int dloc = threadIdx.x >> 2;        // 0..63, local output index

    #pragma unroll 1
    for (int db = 0; db < DIM; db += 64) {
        const int d = db + dloc;
        const int s = start[d];
        const int e = start[d + 1];
        float ax = 0.f, ay = 0.f, az = 0.f, aw = 0.f;
        for (int p = s; p < e; ++p) {
            const int   a  = i1[p];
            const int   b  = i2[p];
            const float sc = scale[p];
            const float4 xv = *reinterpret_cast<const float4*>(xr + a * C + c4);
            const float4 yv = *reinterpret_cast<const float4*>(yr + b * C + c4);
            ax = fmaf(sc * xv.x, yv.x, ax);
            ay = fmaf(sc * xv.y, yv.y, ay);
            az = fmaf(sc * xv.z, yv.z, az);
            aw = fmaf(sc * xv.w, yv.w, aw);
        }
        *reinterpret_cast<float4*>(orow + d * C + c4) = make_float4(ax, ay, az, aw);
    }
}

extern "C" void kernel_launch(void* const* d_in, const int* in_sizes, int n_in,
                              void* d_out, int out_size, void* d_ws, size_t ws_size,
                              hipStream_t stream) {
    const float* x     = (const float*)d_in[0];
    const float* y     = (const float*)d_in[1];
    const float* scale = (const float*)d_in[2];
    const int*   i1    = (const int*)d_in[3];
    const int*   i2    = (const int*)d_in[4];
    const int*   io    = (const int*)d_in[5];
    float* out = (float*)d_out;

    const int nnz = in_sizes[2];
    const int N   = in_sizes[0] / (DIM * C);

    int* start = (int*)d_ws;  // DIM+1 ints

    seg_starts_kernel<<<(DIM + 1 + 255) / 256, 256, 0, stream>>>(io, start, nnz, DIM);
    tp_kernel<<<N, 256, 0, stream>>>(x, y, scale, i1, i2, start, out);
}

// Round 2
// 66.481 us; speedup vs baseline: 3.5886x; 3.5886x over previous
//
#include <hip/hip_runtime.h>

// Problem constants (match the reference file).
constexpr int DIM = 512;   // irreps dim for x, y, out
constexpr int C   = 16;    // channel multiplicity
constexpr int TPB = 1024;  // threads per block (16 waves)

// start[d] = first p such that index_out[p] >= d  (index_out is sorted).
// start[DIM] = nnz. One thread per d in [0, DIM].
__global__ void seg_starts_kernel(const int* __restrict__ io,
                                  int* __restrict__ start,
                                  int nnz, int dim) {
    int d = blockIdx.x * blockDim.x + threadIdx.x;
    if (d > dim) return;
    int lo = 0, hi = nnz;
    while (lo < hi) {
        int mid = (lo + hi) >> 1;
        if (io[mid] < d) lo = mid + 1; else hi = mid;
    }
    start[d] = lo;
}

// One block per n. Stage x-row and y-row (32 KiB each) in LDS, then each
// thread owns (d, c-quad) output elements and walks the sorted segment of
// paths whose index_out == d, gathering operands from LDS. No atomics.
__global__ __launch_bounds__(TPB) void tp_lds_kernel(
    const float* __restrict__ x, const float* __restrict__ y,
    const float* __restrict__ scale,
    const int* __restrict__ i1, const int* __restrict__ i2,
    const int* __restrict__ start,
    float* __restrict__ out) {
    __shared__ float xs[DIM * C];   // 32 KiB
    __shared__ float ys[DIM * C];   // 32 KiB  -> 64 KiB total, 2 blocks/CU

    const int n = blockIdx.x;
    const float4* __restrict__ xr = reinterpret_cast<const float4*>(x + (size_t)n * (DIM * C));
    const float4* __restrict__ yr = reinterpret_cast<const float4*>(y + (size_t)n * (DIM * C));
    float4* xs4 = reinterpret_cast<float4*>(xs);
    float4* ys4 = reinterpret_cast<float4*>(ys);

    // Coalesced staging: DIM*C/4 = 2048 float4 slots per array, 2 per thread.
    #pragma unroll
    for (int i = threadIdx.x; i < DIM * C / 4; i += TPB) {
        xs4[i] = xr[i];
        ys4[i] = yr[i];
    }
    __syncthreads();

    const int c4   = (threadIdx.x & 3) << 2;  // channel quad offset: 0,4,8,12
    const int dloc = threadIdx.x >> 2;        // 0..255, local output index
    float* __restrict__ orow = out + (size_t)n * (DIM * C);

    #pragma unroll
    for (int db = 0; db < DIM; db += TPB / 4) {   // 2 iterations
        const int d = db + dloc;
        const int s = start[d];
        const int e = start[d + 1];
        float ax = 0.f, ay = 0.f, az = 0.f, aw = 0.f;
        for (int p = s; p < e; ++p) {
            const int   a  = i1[p];
            const int   b  = i2[p];
            const float sc = scale[p];
            const float4 xv = *reinterpret_cast<const float4*>(xs + a * C + c4);
            const float4 yv = *reinterpret_cast<const float4*>(ys + b * C + c4);
            ax = fmaf(sc * xv.x, yv.x, ax);
            ay = fmaf(sc * xv.y, yv.y, ay);
            az = fmaf(sc * xv.z, yv.z, az);
            aw = fmaf(sc * xv.w, yv.w, aw);
        }
        *reinterpret_cast<float4*>(orow + d * C + c4) = make_float4(ax, ay, az, aw);
    }
}

extern "C" void kernel_launch(void* const* d_in, const int* in_sizes, int n_in,
                              void* d_out, int out_size, void* d_ws, size_t ws_size,
                              hipStream_t stream) {
    const float* x     = (const float*)d_in[0];
    const float* y     = (const float*)d_in[1];
    const float* scale = (const float*)d_in[2];
    const int*   i1    = (const int*)d_in[3];
    const int*   i2    = (const int*)d_in[4];
    const int*   io    = (const int*)d_in[5];
    float* out = (float*)d_out;

    const int nnz = in_sizes[2];
    const int N   = in_sizes[0] / (DIM * C);

    int* start = (int*)d_ws;  // DIM+1 ints

    seg_starts_kernel<<<(DIM + 1 + 255) / 256, 256, 0, stream>>>(io, start, nnz, DIM);
    tp_lds_kernel<<<N, TPB, 0, stream>>>(x, y, scale, i1, i2, start, out);
}